// Round 7
// baseline (75.297 us; speedup 1.0000x reference)
//
#include <hip/hip_runtime.h>
#include <hip/hip_bf16.h>

#define F_DIM 64
#define B_DIM 64
#define C_DIM 1024
#define THREADS 512

using f32x4  = __attribute__((ext_vector_type(4))) float;
using bf16x8 = __attribute__((ext_vector_type(8))) short;
using s16x4  = __attribute__((ext_vector_type(4))) short;

// fp32 -> bf16 round-to-nearest-even
static __device__ __forceinline__ short f2bf(float f) {
    unsigned u = __float_as_uint(f);
    unsigned r = (u + 0x7fffu + ((u >> 16) & 1u)) >> 16;
    return (short)r;
}

__global__ __launch_bounds__(THREADS, 1)
void channelfc_kernel(const float* __restrict__ x,
                      const float* __restrict__ w,
                      const float* __restrict__ bias,
                      float* __restrict__ out)
{
    // R7: W streamed SEQUENTIALLY, direct global->register as the MFMA
    // B-fragment (lane l holds W[o0+(l&15)][k0+(l>>4)*8+j]) -- no W LDS, no
    // barriers in the K-loop. Every prior round (58-67us across 5 structures)
    // shared one constant: BK=64 => 256B-per-DRAM-page-visit W pattern with
    // ~1.4us revisit gaps. Here each wave sweeps K fully over a 16-row chunk
    // (rolling 4-slot pipeline => consecutive 64-128B pieces of each row are
    // adjacent in the memory queue), and each block's W slab (256 rows x 4KB)
    // is 1MB contiguous, read exactly once chip-wide.
    //
    // T1 XCD swizzle: block n -> XCD n%8; 4 sibling blocks of feature f are
    // n, n+8, n+16, n+24 -> same XCD, launched together -> X_f L2-dedup'd.
    const int n    = blockIdx.x;       // 0..255 (1 block/CU)
    const int xcd  = n & 7;
    const int loc  = n >> 3;           // 0..31
    const int f    = xcd + 8 * (loc >> 2);
    const int q    = loc & 3;          // o-quarter: rows q*256 .. +256

    const int tid  = threadIdx.x;
    const int lane = tid & 63;
    const int wid  = tid >> 6;         // 0..7; wave owns o-rows q*256+wid*32..+32

    // X_f bf16 in LDS, 128 KB, T2 XOR swizzle: (row,byte) at row*2048 + (byte ^ ((row&7)<<4))
    __shared__ short sX[B_DIM * C_DIM];

    const float* xA = x + (size_t)f * C_DIM;                 // + b*(F*C) + c
    const float* wF = w + (size_t)f * C_DIM * C_DIM;         // + o*C + c

    // --- W pipeline state: 4 slots x f32x8 (static indexing only: u is
    // always a compile-time constant after #pragma unroll) ---
    f32x4 wf[4][2];

    const int chunk_o0_base = q * 256 + wid * 32;
    // per-lane W row/col base for a chunk: row = o0+(lane&15), col = (lane>>4)*8 + k0
    const int lrow = lane & 15;
    const int lcol = (lane >> 4) * 8;

    const float* wLane0 = wF + (size_t)(chunk_o0_base + lrow) * C_DIM + lcol;

    // chunk-0 pipeline prologue: slots u <- k0 = u*32 (issued BEFORE X copy
    // so HBM never idles during the prologue)
    #pragma unroll
    for (int u = 0; u < 4; ++u) {
        wf[u][0] = *(const f32x4*)(wLane0 + u * 32);
        wf[u][1] = *(const f32x4*)(wLane0 + u * 32 + 4);
    }

    // --- X_f -> LDS copy (once). 16384 f32x4 / 512 thr = 32/thread. ---
    #pragma unroll 1
    for (int c8 = 0; c8 < 4; ++c8) {
        f32x4 tx[8];
        #pragma unroll
        for (int i = 0; i < 8; ++i) {
            int id = (c8 * 8 + i) * THREADS + tid;
            int row = id >> 8, k4 = id & 255;                 // 256 f32x4 per X row
            tx[i] = *(const f32x4*)(xA + (size_t)row * (F_DIM * C_DIM) + k4 * 4);
        }
        #pragma unroll
        for (int i = 0; i < 8; ++i) {
            int id = (c8 * 8 + i) * THREADS + tid;
            int row = id >> 8, k4 = id & 255;
            int byte = (k4 * 8) ^ ((row & 7) << 4);
            s16x4 v; v[0]=f2bf(tx[i][0]); v[1]=f2bf(tx[i][1]); v[2]=f2bf(tx[i][2]); v[3]=f2bf(tx[i][3]);
            *(s16x4*)((char*)&sX[0] + row * 2048 + byte) = v;
        }
    }
    __syncthreads();   // the ONLY barrier; K-loop below is barrier-free

    // --- main: 2 chunks of 16 o-rows; per chunk sweep full K with rolling
    // 4-deep W pipeline; acc[mt] covers b = mt*16..+16 (all 64 batches). ---
    #pragma unroll 1
    for (int c = 0; c < 2; ++c) {
        const int o0 = chunk_o0_base + c * 16;
        const float* wLane = wF + (size_t)(o0 + lrow) * C_DIM + lcol;
        if (c == 1) {   // refill pipeline for this chunk
            #pragma unroll
            for (int u = 0; u < 4; ++u) {
                wf[u][0] = *(const f32x4*)(wLane + u * 32);
                wf[u][1] = *(const f32x4*)(wLane + u * 32 + 4);
            }
        }
        f32x4 acc[4] = {};
        #pragma unroll 1
        for (int kb = 0; kb < 8; ++kb) {
            #pragma unroll
            for (int u = 0; u < 4; ++u) {
                const int k0 = kb * 128 + u * 32;
                // cvt slot -> bf16 B-fragment
                bf16x8 bw;
                bw[0]=f2bf(wf[u][0][0]); bw[1]=f2bf(wf[u][0][1]); bw[2]=f2bf(wf[u][0][2]); bw[3]=f2bf(wf[u][0][3]);
                bw[4]=f2bf(wf[u][1][0]); bw[5]=f2bf(wf[u][1][1]); bw[6]=f2bf(wf[u][1][2]); bw[7]=f2bf(wf[u][1][3]);
                // reload slot for k0+128 (keeps 4 sequential loads in flight)
                if (kb < 7) {
                    wf[u][0] = *(const f32x4*)(wLane + k0 + 128);
                    wf[u][1] = *(const f32x4*)(wLane + k0 + 128 + 4);
                }
                // A-fragments from LDS: row = mt*16+(lane&15), k = k0+(lane>>4)*8+j
                const int kbyte = k0 * 2 + (lane >> 4) * 16;
                #pragma unroll
                for (int mt = 0; mt < 4; ++mt) {
                    const int row = mt * 16 + lrow;
                    bf16x8 af = *(const bf16x8*)((const char*)&sX[0] + row * 2048 + (kbyte ^ ((row & 7) << 4)));
                    acc[mt] = __builtin_amdgcn_mfma_f32_16x16x32_bf16(af, bw, acc[mt], 0, 0, 0);
                }
            }
        }
        // epilogue: C/D layout (m89-verified): col = lane&15 -> o, row = (lane>>4)*4 + r -> b (within mt*16)
        const int o  = o0 + lrow;
        const float bv = bias[f * C_DIM + o];
        #pragma unroll
        for (int mt = 0; mt < 4; ++mt) {
            #pragma unroll
            for (int r = 0; r < 4; ++r) {
                const int b = mt * 16 + (lane >> 4) * 4 + r;
                out[((size_t)b * F_DIM + f) * C_DIM + o] = acc[mt][r] + bv;
            }
        }
    }
}

extern "C" void kernel_launch(void* const* d_in, const int* in_sizes, int n_in,
                              void* d_out, int out_size, void* d_ws, size_t ws_size,
                              hipStream_t stream) {
    const float* x    = (const float*)d_in[0];
    const float* w    = (const float*)d_in[1];
    const float* bias = (const float*)d_in[2];
    float* out        = (float*)d_out;
    // 256 blocks = 1/CU (128 KiB LDS each); XCD-aware decode in-kernel.
    channelfc_kernel<<<dim3(256), dim3(THREADS), 0, stream>>>(x, w, bias, out);
}

// Round 8
// 63.430 us; speedup vs baseline: 1.1871x; 1.1871x over previous
//
#include <hip/hip_runtime.h>
#include <hip/hip_bf16.h>

#define F_DIM 64
#define B_DIM 64
#define C_DIM 1024
#define BM 64
#define BN 128
#define BK 128
#define NT (C_DIM / BK)       // 8 K-steps
#define NTILES (C_DIM / BN)   // 8 o-tiles per feature
#define THREADS 512

using f32x4  = __attribute__((ext_vector_type(4))) float;
using bf16x8 = __attribute__((ext_vector_type(8))) short;
using s16x4  = __attribute__((ext_vector_type(4))) short;

// fp32 -> bf16 round-to-nearest-even
static __device__ __forceinline__ short f2bf(float f) {
    unsigned u = __float_as_uint(f);
    unsigned r = (u + 0x7fffu + ((u >> 16) & 1u)) >> 16;
    return (short)r;
}

__global__ __launch_bounds__(THREADS, 4)
void channelfc_kernel(const float* __restrict__ x,
                      const float* __restrict__ w,
                      const float* __restrict__ bias,
                      float* __restrict__ out)
{
    // R8: single change vs R5 (58.3us): BK 64 -> 128. Tests the last live
    // theory for the 8.4 vs 11.2 B/cy/CU gap -- DRAM chunk granularity. Each
    // W/X row is now visited with ONE 512B-contiguous chunk per K-step (one
    // instruction: 32 lanes x 16B) instead of two 256B visits 1.4us apart;
    // page re-activations per 4KB row halve. Geometry/traffic otherwise
    // identical: 512 blocks (2/CU), 8 waves, coalesced staging, T2 swizzle.
    // LDS single-buffered 48KB (2 barriers/step x 8 steps = same 16 barriers).
    //
    // T1 XCD swizzle: block n -> XCD n%8; XCD x owns features {x, x+8, ...},
    // 8 o-tiles of one f consecutive -> X_f (256 KB) fetched ~once per XCD.
    const int n    = blockIdx.x;       // 0..511
    const int xcd  = n & 7;
    const int j    = n >> 3;           // 0..63 within this XCD
    const int f    = xcd + 8 * (j >> 3);
    const int bx   = j & 7;            // o-tile index
    const int ocol0 = bx * BN;

    const int tid   = threadIdx.x;
    const int lane  = tid & 63;
    const int wid   = tid >> 6;   // 0..7
    const int wr    = wid >> 2;   // 0..1 -> rows wr*32..+32
    const int wc    = wid & 3;    // 0..3 -> cols wc*32..+32

    // bf16 tiles, row stride 256B. T2 XOR swizzle: (row, byte) at
    // row*256 + (byte ^ ((row&7)<<4)) -- rows r, r+8 share a 16B slot
    // (2-way, free per m136); without swizzle 16 lanes hit one bank group.
    __shared__ short sX[BM * BK];   // 16 KB (X tile: row = b, col = k)
    __shared__ short sW[BN * BK];   // 32 KB (W tile: row = o, col = k)

    const float* xA = x + (size_t)f * C_DIM;                       // + b*(F*C) + c
    const float* wB = w + ((size_t)f * C_DIM + ocol0) * C_DIM;     // + o*C + c

    f32x4 ra[4];   // X staging: 2048 f32x4 / 512 thr = 4 each
    f32x4 rb[8];   // W staging: 4096 f32x4 / 512 thr = 8 each

    // Mapping: id = i*512+tid -> row = id>>5, k4 = id&31 (32 f32x4 = 512B/row).
    // One instruction covers 2 full rows x 512B contiguous -> the memory
    // system sees 512B sequential segments (the point of this round).
    auto load_tile = [&](int t) {
        const int k0 = t * BK;
        #pragma unroll
        for (int i = 0; i < 4; ++i) {
            int id = i * THREADS + tid, row = id >> 5, k4 = id & 31;
            ra[i] = *(const f32x4*)(xA + (size_t)row * (F_DIM * C_DIM) + k0 + k4 * 4);
        }
        #pragma unroll
        for (int i = 0; i < 8; ++i) {
            int id = i * THREADS + tid, row = id >> 5, k4 = id & 31;
            rb[i] = *(const f32x4*)(wB + (size_t)row * C_DIM + k0 + k4 * 4);
        }
    };

    auto store_tile = [&]() {
        #pragma unroll
        for (int i = 0; i < 4; ++i) {
            int id = i * THREADS + tid, row = id >> 5, k4 = id & 31;
            int byte = (k4 * 8) ^ ((row & 7) << 4);
            s16x4 v; v[0]=f2bf(ra[i][0]); v[1]=f2bf(ra[i][1]); v[2]=f2bf(ra[i][2]); v[3]=f2bf(ra[i][3]);
            *(s16x4*)((char*)&sX[0] + row * 256 + byte) = v;
        }
        #pragma unroll
        for (int i = 0; i < 8; ++i) {
            int id = i * THREADS + tid, row = id >> 5, k4 = id & 31;
            int byte = (k4 * 8) ^ ((row & 7) << 4);
            s16x4 v; v[0]=f2bf(rb[i][0]); v[1]=f2bf(rb[i][1]); v[2]=f2bf(rb[i][2]); v[3]=f2bf(rb[i][3]);
            *(s16x4*)((char*)&sW[0] + row * 256 + byte) = v;
        }
    };

    f32x4 acc[2][2] = {};   // wave sub-tile 32x32 = 2 M-frags x 2 N-frags

    auto compute = [&]() {
        #pragma unroll
        for (int ks = 0; ks < 4; ++ks) {
            const int kbyte = ks * 64 + (lane >> 4) * 16;   // frag: k = ks*32 + (lane>>4)*8 + j
            bf16x8 af[2], bfr[2];
            #pragma unroll
            for (int mt = 0; mt < 2; ++mt) {
                int row = wr * 32 + mt * 16 + (lane & 15);
                af[mt] = *(const bf16x8*)((const char*)&sX[0] + row * 256 + (kbyte ^ ((row & 7) << 4)));
            }
            #pragma unroll
            for (int nt = 0; nt < 2; ++nt) {
                int row = wc * 32 + nt * 16 + (lane & 15);
                bfr[nt] = *(const bf16x8*)((const char*)&sW[0] + row * 256 + (kbyte ^ ((row & 7) << 4)));
            }
            #pragma unroll
            for (int mt = 0; mt < 2; ++mt)
                #pragma unroll
                for (int nt = 0; nt < 2; ++nt)
                    acc[mt][nt] = __builtin_amdgcn_mfma_f32_16x16x32_bf16(af[mt], bfr[nt], acc[mt][nt], 0, 0, 0);
        }
    };

    // Single-buffer, 2 barriers/step: barrier(a) = compute(t-1) finished its
    // LDS reads in every wave (lgkmcnt drained pre-barrier) -> safe to
    // overwrite; barrier(b) = tile t fully staged -> safe to read. Loads for
    // t+1 are issued between store and barrier(b), landing during compute(t).
    load_tile(0);
    #pragma unroll 1
    for (int t = 0; t < NT; ++t) {
        __syncthreads();                    // (a)
        store_tile();
        if (t + 1 < NT) load_tile(t + 1);
        __syncthreads();                    // (b)
        compute();
    }

    // Epilogue. C/D layout (m89-verified): col = lane&15 (-> o), row = (lane>>4)*4 + reg (-> b)
    const int ncol_base = ocol0 + wc * 32 + (lane & 15);
    const int mrow_base = wr * 32 + (lane >> 4) * 4;
    #pragma unroll
    for (int nt = 0; nt < 2; ++nt) {
        const int o  = ncol_base + nt * 16;
        const float bv = bias[f * C_DIM + o];
        #pragma unroll
        for (int mt = 0; mt < 2; ++mt) {
            #pragma unroll
            for (int r = 0; r < 4; ++r) {
                const int b = mrow_base + mt * 16 + r;
                out[((size_t)b * F_DIM + f) * C_DIM + o] = acc[mt][nt][r] + bv;
            }
        }
    }
}

extern "C" void kernel_launch(void* const* d_in, const int* in_sizes, int n_in,
                              void* d_out, int out_size, void* d_ws, size_t ws_size,
                              hipStream_t stream) {
    const float* x    = (const float*)d_in[0];
    const float* w    = (const float*)d_in[1];
    const float* bias = (const float*)d_in[2];
    float* out        = (float*)d_out;
    // 512 blocks (2/CU), XCD-aware index decode in-kernel.
    channelfc_kernel<<<dim3(NTILES * F_DIM), dim3(THREADS), 0, stream>>>(x, w, bias, out);
}

// Round 9
// 59.387 us; speedup vs baseline: 1.2679x; 1.0681x over previous
//
#include <hip/hip_runtime.h>
#include <hip/hip_bf16.h>

#define F_DIM 64
#define B_DIM 64
#define C_DIM 1024
#define BM 64
#define BN 128
#define BK 64
#define NT (C_DIM / BK)       // 16 K-steps
#define NTILES (C_DIM / BN)   // 8 o-tiles per feature
#define THREADS 512

using f32x4  = __attribute__((ext_vector_type(4))) float;
using bf16x8 = __attribute__((ext_vector_type(8))) short;
using s16x4  = __attribute__((ext_vector_type(4))) short;

// fp32 -> bf16 round-to-nearest-even
static __device__ __forceinline__ short f2bf(float f) {
    unsigned u = __float_as_uint(f);
    unsigned r = (u + 0x7fffu + ((u >> 16) & 1u)) >> 16;
    return (short)r;
}

// T4 barrier: __syncthreads() lowers to "s_waitcnt vmcnt(0) lgkmcnt(0);
// s_barrier" (m97 asm) -- the vmcnt(0) drains our t+1 register prefetch at
// EVERY step, re-exposing HBM latency+queue refill each iteration (~20%
// structural stall, the m97 mechanism). Raw s_barrier + lgkmcnt(0)-only
// keeps all LDS ordering (ds_writes drained; ds_read->MFMA deps are
// compiler-managed) while global->REGISTER loads stay in flight across the
// barrier. Register loads need no barrier drain: tile-t consumption is
// ordered by register dependencies inside store_tile.
static __device__ __forceinline__ void barrier_lds_only() {
    asm volatile("s_waitcnt lgkmcnt(0)" ::: "memory");
    __builtin_amdgcn_s_barrier();
}

__global__ __launch_bounds__(THREADS, 4)
void channelfc_kernel(const float* __restrict__ x,
                      const float* __restrict__ w,
                      const float* __restrict__ bias,
                      float* __restrict__ out)
{
    // R9: single change vs R5 (58.3us): counted-drain barrier (see above).
    // Geometry identical: BN=128, BK=64, 512 blocks (2/CU), 8 waves/block,
    // reg-staged fp32->bf16->LDS, T2 swizzle, double-buffered LDS.
    //
    // T1 XCD swizzle: block n -> XCD n%8; XCD x owns features {x, x+8, ...},
    // 8 o-tiles of one f consecutive -> X_f (256 KB) fetched ~once per XCD.
    const int n    = blockIdx.x;       // 0..511
    const int xcd  = n & 7;
    const int j    = n >> 3;           // 0..63 within this XCD
    const int f    = xcd + 8 * (j >> 3);
    const int bx   = j & 7;            // o-tile index
    const int ocol0 = bx * BN;

    const int tid   = threadIdx.x;
    const int lane  = tid & 63;
    const int wid   = tid >> 6;   // 0..7
    const int wr    = wid >> 2;   // 0..1 -> rows wr*32..+32
    const int wc    = wid & 3;    // 0..3 -> cols wc*32..+32

    // bf16 tiles, T2 XOR swizzle: (row, byte) lives at row*128 + (byte ^ ((row&7)<<4))
    __shared__ short sA[2][BM * BK];   // 8 KB per buffer  (X tile: row = b, col = k)
    __shared__ short sB[2][BN * BK];   // 16 KB per buffer (W tile: row = o, col = k)

    const float* xA = x + (size_t)f * C_DIM;                       // + b*(F*C) + c
    const float* wB = w + ((size_t)f * C_DIM + ocol0) * C_DIM;     // + o*C + c

    f32x4 ra[2];   // X staging: 1024 float4 / 512 thr = 2 each
    f32x4 rb[4];   // W staging: 2048 float4 / 512 thr = 4 each

    auto load_tile = [&](int t) {
        const int k0 = t * BK;
        #pragma unroll
        for (int i = 0; i < 2; ++i) {
            int id = i * THREADS + tid, row = id >> 4, k4 = id & 15;   // 16 float4 per row
            ra[i] = *(const f32x4*)(xA + (size_t)row * (F_DIM * C_DIM) + k0 + k4 * 4);
        }
        #pragma unroll
        for (int i = 0; i < 4; ++i) {
            int id = i * THREADS + tid, row = id >> 4, k4 = id & 15;
            rb[i] = *(const f32x4*)(wB + (size_t)row * C_DIM + k0 + k4 * 4);
        }
    };

    auto store_tile = [&](int buf) {
        #pragma unroll
        for (int i = 0; i < 2; ++i) {
            int id = i * THREADS + tid, row = id >> 4, k4 = id & 15;
            int byte = (k4 * 8) ^ ((row & 7) << 4);                // 8B store, swizzle 16B-granular
            s16x4 v; v[0]=f2bf(ra[i][0]); v[1]=f2bf(ra[i][1]); v[2]=f2bf(ra[i][2]); v[3]=f2bf(ra[i][3]);
            *(s16x4*)((char*)&sA[buf][0] + row * 128 + byte) = v;
        }
        #pragma unroll
        for (int i = 0; i < 4; ++i) {
            int id = i * THREADS + tid, row = id >> 4, k4 = id & 15;
            int byte = (k4 * 8) ^ ((row & 7) << 4);
            s16x4 v; v[0]=f2bf(rb[i][0]); v[1]=f2bf(rb[i][1]); v[2]=f2bf(rb[i][2]); v[3]=f2bf(rb[i][3]);
            *(s16x4*)((char*)&sB[buf][0] + row * 128 + byte) = v;
        }
    };

    f32x4 acc[2][2] = {};   // wave sub-tile 32x32 = 2 M-frags x 2 N-frags

    auto compute = [&](int buf) {
        #pragma unroll
        for (int ks = 0; ks < 2; ++ks) {
            const int kbyte = ks * 64 + (lane >> 4) * 16;   // frag: k = ks*32 + (lane>>4)*8 + j
            bf16x8 af[2], bfr[2];
            #pragma unroll
            for (int mt = 0; mt < 2; ++mt) {
                int row = wr * 32 + mt * 16 + (lane & 15);
                af[mt] = *(const bf16x8*)((const char*)&sA[buf][0] + row * 128 + (kbyte ^ ((row & 7) << 4)));
            }
            #pragma unroll
            for (int nt = 0; nt < 2; ++nt) {
                int row = wc * 32 + nt * 16 + (lane & 15);
                bfr[nt] = *(const bf16x8*)((const char*)&sB[buf][0] + row * 128 + (kbyte ^ ((row & 7) << 4)));
            }
            #pragma unroll
            for (int mt = 0; mt < 2; ++mt)
                #pragma unroll
                for (int nt = 0; nt < 2; ++nt)
                    acc[mt][nt] = __builtin_amdgcn_mfma_f32_16x16x32_bf16(af[mt], bfr[nt], acc[mt][nt], 0, 0, 0);
        }
    };

    // Barrier safety (1 barrier/step, 2 LDS bufs): compute(t) reads buf[t&1]
    // after barrier(t), which store(t) wrote before it (ds_writes drained by
    // lgkmcnt(0)); store(t+2) overwrites buf[t&1] only after barrier(t+1),
    // and every wave's compute(t) MFMAs issued before barrier(t+1) implies
    // their ds_reads completed (lgkmcnt dep waits precede each MFMA issue).
    load_tile(0);
    for (int t = 0; t < NT; ++t) {
        const int buf = t & 1;
        store_tile(buf);                    // reg deps force waits on tile-t loads only
        if (t + 1 < NT) load_tile(t + 1);   // stays in flight ACROSS the barrier now
        barrier_lds_only();
        compute(buf);
    }

    // Epilogue. C/D layout (m89-verified): col = lane&15 (-> o), row = (lane>>4)*4 + reg (-> b)
    const int ncol_base = ocol0 + wc * 32 + (lane & 15);
    const int mrow_base = wr * 32 + (lane >> 4) * 4;
    #pragma unroll
    for (int nt = 0; nt < 2; ++nt) {
        const int o  = ncol_base + nt * 16;
        const float bv = bias[f * C_DIM + o];
        #pragma unroll
        for (int mt = 0; mt < 2; ++mt) {
            #pragma unroll
            for (int r = 0; r < 4; ++r) {
                const int b = mrow_base + mt * 16 + r;
                out[((size_t)b * F_DIM + f) * C_DIM + o] = acc[mt][nt][r] + bv;
            }
        }
    }
}

extern "C" void kernel_launch(void* const* d_in, const int* in_sizes, int n_in,
                              void* d_out, int out_size, void* d_ws, size_t ws_size,
                              hipStream_t stream) {
    const float* x    = (const float*)d_in[0];
    const float* w    = (const float*)d_in[1];
    const float* bias = (const float*)d_in[2];
    float* out        = (float*)d_out;
    // 512 blocks (2/CU), XCD-aware index decode in-kernel.
    channelfc_kernel<<<dim3(NTILES * F_DIM), dim3(THREADS), 0, stream>>>(x, w, bias, out);
}